// Round 2
// baseline (346.334 us; speedup 1.0000x reference)
//
#include <hip/hip_runtime.h>
#include <math.h>

// Problem constants
#define BB 512
#define TT 2048
#define AA 16
#define NTOT (512LL * 2048LL * 16LL)   // 16,777,216 elements
#define NV4  (NTOT / 4)                // 4,194,304 float4s
#define GAMMA 0.99f
#define GLAM  0.9405f                  // gamma * lam
#define ENTC  1.4189385332046727f      // 0.5 + 0.5*log(2*pi)

#define NB2   4096                     // blocks for obj kernel
#define ITER2 4                        // float4 iterations per thread
#define S2    (NB2 * 256)              // float4 stride between iterations

// ---------------------------------------------------------------------------
// K1: GAE via parallel affine scan. One block (256 threads) per batch row.
// Thread tid owns u in [8*tid, 8*tid+8), u = T-1-t (reversed recurrence
// y_u = a_u*y_{u-1} + b_u;  u==0 -> (0,0)).
// Loads are vectorized in t-space (cacheline-exact fetch).
// ---------------------------------------------------------------------------
__global__ __launch_bounds__(256) void gae_kernel(
    const float* __restrict__ rewards, const float* __restrict__ vout,
    const int* __restrict__ dones, float* __restrict__ adv)
{
    const int b   = blockIdx.x;
    const int tid = threadIdx.x;
    const float* rw = rewards + (size_t)b * TT;
    const float* V  = vout    + (size_t)b * (TT + 1);
    const int*   dn = dones   + (size_t)b * TT;
    float*       av = adv     + (size_t)b * TT;

    // t-range for this thread: [tb, tb+7], tb = 2040 - 8*tid (multiple of 8)
    const int tb = (TT - 8) - 8 * tid;

    const float4 r0 = ((const float4*)(rw + tb))[0];
    const float4 r1 = ((const float4*)(rw + tb))[1];
    const float4 v0 = ((const float4*)(V  + tb))[0];
    const float4 v1 = ((const float4*)(V  + tb))[1];
    const float  v8 = V[tb + 8];
    const int4   d0 = ((const int4*)(dn + tb))[0];
    const int4   d1 = ((const int4*)(dn + tb))[1];
    const int    d8 = (tid > 0) ? dn[tb + 8] : 0;   // dn[2048] OOB guard (u==0 case)

    float r_[8] = {r0.x, r0.y, r0.z, r0.w, r1.x, r1.y, r1.z, r1.w};
    float v_[9] = {v0.x, v0.y, v0.z, v0.w, v1.x, v1.y, v1.z, v1.w, v8};
    int   d_[9] = {d0.x, d0.y, d0.z, d0.w, d1.x, d1.y, d1.z, d1.w, d8};

    float ak[8], bk[8];
    float SA = 1.f, SB = 0.f;          // segment composite (earliest-first)
    #pragma unroll
    for (int k = 0; k < 8; ++k) {
        const int j = 7 - k;           // t = tb + j, u = 8*tid + k
        float au, bu;
        if (tid == 0 && k == 0) { au = 0.f; bu = 0.f; }   // u == 0
        else {
            bu = r_[j] + GAMMA * v_[j + 1] - v_[j];
            au = GLAM * (1.f - (float)d_[j + 1]);
        }
        ak[k] = au; bk[k] = bu;
        SB = au * SB + bu;
        SA = au * SA;
    }

    const int lane = tid & 63;
    const int wave = tid >> 6;

    // wave-inclusive scan of composites
    #pragma unroll
    for (int off = 1; off < 64; off <<= 1) {
        float pA = __shfl_up(SA, off, 64);
        float pB = __shfl_up(SB, off, 64);
        if (lane >= off) { SB = SA * pB + SB; SA = SA * pA; }
    }

    __shared__ float wA[4], wB[4];
    if (lane == 63) { wA[wave] = SA; wB[wave] = SB; }
    __syncthreads();

    float PA = 1.f, PB = 0.f;
    for (int w = 0; w < wave; ++w) {
        float aw = wA[w], bw = wB[w];
        PB = aw * PB + bw;
        PA = aw * PA;
    }

    float EA = __shfl_up(SA, 1, 64);
    float EB = __shfl_up(SB, 1, 64);
    if (lane == 0) { EA = 1.f; EB = 0.f; }

    float x = EA * PB + EB;            // carry into my segment
    float xv[8];
    #pragma unroll
    for (int k = 0; k < 8; ++k) {
        x = ak[k] * x + bk[k];
        xv[k] = x;
    }
    // t order = reverse k order
    float4 o0 = {xv[7], xv[6], xv[5], xv[4]};   // t = tb..tb+3
    float4 o1 = {xv[3], xv[2], xv[1], xv[0]};   // t = tb+4..tb+7
    ((float4*)(av + tb))[0] = o0;
    ((float4*)(av + tb))[1] = o1;
}

// ---------------------------------------------------------------------------
// K2: PPO objective partial sums. clipped == 0.8 (faithful clip bug).
// All 24 loads issued up front (full unroll), 4 independent f32 accumulators.
// ---------------------------------------------------------------------------
__device__ __forceinline__ float obj1(float x, float m, float s,
                                      float om, float os, float ad)
{
    float rs  = __builtin_amdgcn_rcpf(s);
    float ros = __builtin_amdgcn_rcpf(os);
    float z   = (x - m) * rs;
    float zo  = (x - om) * ros;
    float d   = 0.5f * (zo * zo - z * z);
    float ratio = os * rs * __expf(d);
    return fminf(ad * ratio, ad * 0.8f);
}

__global__ __launch_bounds__(256) void obj_kernel(
    const float* __restrict__ mu, const float* __restrict__ sigma,
    const float* __restrict__ old_mu, const float* __restrict__ old_sigma,
    const float* __restrict__ actions, const float* __restrict__ adv,
    double* __restrict__ partials)
{
    const int tid = threadIdx.x;
    const size_t g = (size_t)blockIdx.x * 256 + tid;

    const float4* m4  = (const float4*)mu;
    const float4* s4  = (const float4*)sigma;
    const float4* om4 = (const float4*)old_mu;
    const float4* os4 = (const float4*)old_sigma;
    const float4* x4  = (const float4*)actions;

    float4 m[ITER2], s[ITER2], om[ITER2], os[ITER2], x[ITER2];
    float ad[ITER2];
    #pragma unroll
    for (int k = 0; k < ITER2; ++k) {
        size_t v = g + (size_t)k * S2;
        m[k]  = m4[v];
        s[k]  = s4[v];
        om[k] = om4[v];
        os[k] = os4[v];
        x[k]  = x4[v];
        ad[k] = adv[v >> 2];
    }

    float a0 = 0.f, a1 = 0.f, a2 = 0.f, a3 = 0.f;
    #pragma unroll
    for (int k = 0; k < ITER2; ++k) {
        a0 += obj1(x[k].x, m[k].x, s[k].x, om[k].x, os[k].x, ad[k]);
        a1 += obj1(x[k].y, m[k].y, s[k].y, om[k].y, os[k].y, ad[k]);
        a2 += obj1(x[k].z, m[k].z, s[k].z, om[k].z, os[k].z, ad[k]);
        a3 += obj1(x[k].w, m[k].w, s[k].w, om[k].w, os[k].w, ad[k]);
    }
    double lsum = ((double)a0 + (double)a1) + ((double)a2 + (double)a3);

    #pragma unroll
    for (int off = 32; off > 0; off >>= 1)
        lsum += __shfl_down(lsum, off, 64);

    __shared__ double wsum[4];
    const int lane = tid & 63, wave = tid >> 6;
    if (lane == 0) wsum[wave] = lsum;
    __syncthreads();
    if (tid == 0)
        partials[blockIdx.x] = wsum[0] + wsum[1] + wsum[2] + wsum[3];
}

// ---------------------------------------------------------------------------
// K2b: reduce NB2 partials -> mean (single block)
// ---------------------------------------------------------------------------
__global__ __launch_bounds__(256) void reduce_kernel(
    const double* __restrict__ partials, float* __restrict__ meanOut)
{
    const int tid = threadIdx.x;
    double s = 0.0;
    for (int i = tid; i < NB2; i += 256) s += partials[i];
    #pragma unroll
    for (int off = 32; off > 0; off >>= 1)
        s += __shfl_down(s, off, 64);
    __shared__ double wsum[4];
    const int lane = tid & 63, wave = tid >> 6;
    if (lane == 0) wsum[wave] = s;
    __syncthreads();
    if (tid == 0) {
        double total = wsum[0] + wsum[1] + wsum[2] + wsum[3];
        meanOut[0] = (float)(total / (double)NTOT);
    }
}

// ---------------------------------------------------------------------------
// K3: out[i] = mean + log(sigma[i]) + ENTC. 4 independent streams per thread.
// ---------------------------------------------------------------------------
__global__ __launch_bounds__(256) void out_kernel(
    const float* __restrict__ sigma, const float* __restrict__ meanPtr,
    float* __restrict__ out)
{
    const size_t g = (size_t)blockIdx.x * 256 + threadIdx.x;
    const float mean = meanPtr[0];
    const float4* s4 = (const float4*)sigma;
    float4* o4 = (float4*)out;
    #pragma unroll
    for (int k = 0; k < ITER2; ++k) {
        size_t v = g + (size_t)k * S2;
        float4 s = s4[v];
        float4 o;
        o.x = mean + __logf(s.x) + ENTC;
        o.y = mean + __logf(s.y) + ENTC;
        o.z = mean + __logf(s.z) + ENTC;
        o.w = mean + __logf(s.w) + ENTC;
        o4[v] = o;
    }
}

// ---------------------------------------------------------------------------
extern "C" void kernel_launch(void* const* d_in, const int* in_sizes, int n_in,
                              void* d_out, int out_size, void* d_ws, size_t ws_size,
                              hipStream_t stream) {
    const float* rewards   = (const float*)d_in[0];   // [B,T]
    const float* critic    = (const float*)d_in[1];   // [B,T+1]
    const float* mu        = (const float*)d_in[2];   // [B,T,A]
    const float* sigma     = (const float*)d_in[3];
    const float* old_mu    = (const float*)d_in[4];
    const float* old_sigma = (const float*)d_in[5];
    const float* actions   = (const float*)d_in[6];
    const int*   dones     = (const int*)d_in[7];     // [B,T]
    float* out = (float*)d_out;

    char* ws = (char*)d_ws;
    float*  meanPtr  = (float*)ws;                    // 4 B
    double* partials = (double*)(ws + 256);           // 32 KB (NB2 doubles)
    float*  adv      = (float*)(ws + 65536);          // 4 MB (B*T floats)

    gae_kernel<<<BB, 256, 0, stream>>>(rewards, critic, dones, adv);
    obj_kernel<<<NB2, 256, 0, stream>>>(mu, sigma, old_mu, old_sigma,
                                        actions, adv, partials);
    reduce_kernel<<<1, 256, 0, stream>>>(partials, meanPtr);
    out_kernel<<<NB2, 256, 0, stream>>>(sigma, meanPtr, out);
}